// Round 4
// baseline (334.219 us; speedup 1.0000x reference)
//
#include <hip/hip_runtime.h>
#include <hip/hip_bf16.h>
#include <stdint.h>

#define BATCH 4096
#define TLEN  1024
#define MSTR  72     // LDS stride (bf16 elems) for T matrices; 144B keeps b64/b128 alignment
#define CSTR  68     // combine buffer stride (f32); 272B keeps f32x4 alignment

// ---- LDS layout (bytes) ----
#define OFF_T    0        // Tsm plain [64][MSTR] bf16   (bwd A source)
#define OFF_G    9216     // Tsm^T     [64][MSTR] bf16   (fwd A source)
#define OFF_PE   18432    // float pE[2][64]
#define OFF_PIV  18944    // float piv[64]
#define OFF_YB   19200    // u64 yball[32][16] = 4096
#define OFF_CMB  23296    // float gamma[32][CSTR] = 8704
#define OFF_LACB 32000    // float laccB[32]
#define SMEM_SZ  32128

typedef short        bf16x4 __attribute__((ext_vector_type(4)));
typedef short        bf16x8 __attribute__((ext_vector_type(8)));
typedef float        f32x4  __attribute__((ext_vector_type(4)));
typedef unsigned int u32;
typedef unsigned int u32x4  __attribute__((ext_vector_type(4)));

#define MFMA(a,b,c) __builtin_amdgcn_mfma_f32_16x16x32_bf16(a,b,c,0,0,0)

// Pack two f32 -> one u32 of 2x bf16 (RNE), pure register ops (SROA-safe).
static __device__ __forceinline__ u32 packpair(float lo, float hi) {
    const u32 l = (u32)__builtin_bit_cast(unsigned short, __float2bfloat16(lo));
    const u32 h = (u32)__builtin_bit_cast(unsigned short, __float2bfloat16(hi));
    return l | (h << 16);
}

// ---------------------------------------------------------------------------
// 128 wgs x 128 thr (2 waves). wg = 32-batch block [R0, R0+32):
//   wave0: TWO interleaved forward alpha-chains  (cols 0-15 = X, 16-31 = Y)
//   wave1: TWO interleaved backward gamma-chains (same split)
// A-fragments and e-vectors are shared between a wave's two chains; only
// d/t/bit-stream state doubles. The two chains' dependency graphs interleave
// in one instruction stream, filling the serial-recurrence stall bubbles
// (round-3 post-mortem: 765 cy/step at 45% idle with ONE chain per wave).
// Register-only chain exactly as round 3: MFMA D-fragment repacked directly
// as next step's B-fragment; A gathered once with k-slot permutation
// sigma(h,g,j)=32h+4g+(j&3)+16(j>>2). Renorm every 16 steps. Combine in-wg.
// ---------------------------------------------------------------------------
__global__ __launch_bounds__(128, 1) void hmm_fb(
    const int* __restrict__ y, const float* __restrict__ Tmat,
    const float* __restrict__ Emat, const float* __restrict__ Pi,
    float* __restrict__ out)
{
    __shared__ __align__(16) unsigned char SM[SMEM_SZ];

    const int tid  = threadIdx.x;
    const int wv   = tid >> 6;          // 0 = fwd, 1 = bwd
    const int lane = tid & 63;
    const int lr   = lane & 15;         // batch col within 16-wide chain
    const int g    = lane >> 4;         // k-group
    const int R0   = blockIdx.x << 5;   // 32 batches per wg

    float* pE  = (float*)(SM + OFF_PE);
    float* piv = (float*)(SM + OFF_PIV);
    const f32x4 zero = {0.f, 0.f, 0.f, 0.f};

    // ---- phase 0: emission + pi softmax ----
    if (tid < 64) {
        const float e0 = Emat[tid*2+0], e1 = Emat[tid*2+1];
        const float em = fmaxf(e0, e1);
        const float p0 = __expf(e0-em), p1 = __expf(e1-em);
        const float ez = 1.0f / (p0 + p1);
        pE[tid]      = p0 * ez;
        pE[64 + tid] = p1 * ez;
        float v = Pi[tid];
        float mx = v;
        #pragma unroll
        for (int d = 1; d < 64; d <<= 1) mx = fmaxf(mx, __shfl_xor(mx, d));
        const float e = __expf(v - mx);
        float z = e;
        #pragma unroll
        for (int d = 1; d < 64; d <<= 1) z += __shfl_xor(z, d);
        piv[tid] = e / z;
    }

    // ---- phase 1: row-softmax of T -> plain + transposed bf16 ----
    {
        const int r  = tid >> 1;          // 0..63
        const int hh = tid & 1;           // 32-col half
        float v[32];
        #pragma unroll
        for (int q = 0; q < 8; q++) {
            const float4 t4 = *(const float4*)(Tmat + r*64 + hh*32 + q*4);
            v[q*4+0]=t4.x; v[q*4+1]=t4.y; v[q*4+2]=t4.z; v[q*4+3]=t4.w;
        }
        float mx = v[0];
        #pragma unroll
        for (int k = 1; k < 32; k++) mx = fmaxf(mx, v[k]);
        mx = fmaxf(mx, __shfl_xor(mx, 1));
        float z = 0.f;
        #pragma unroll
        for (int k = 0; k < 32; k++) { v[k] = __expf(v[k]-mx); z += v[k]; }
        z += __shfl_xor(z, 1);
        const float inv = 1.0f / z;
        __hip_bfloat16* Tsm = (__hip_bfloat16*)(SM + OFF_T);
        __hip_bfloat16* Gt  = (__hip_bfloat16*)(SM + OFF_G);
        #pragma unroll
        for (int k = 0; k < 32; k++) {
            const int j = hh*32 + k;
            const __hip_bfloat16 hb = __float2bfloat16(v[k] * inv);
            Tsm[r*MSTR + j] = hb;     // Tsm[s][s']
            Gt[j*MSTR + r]  = hb;     // Gt[s'][s] = T[s][s']
        }
    }
    __syncthreads();

    // ---- phase 2: gather permuted A-fragments (shared by both chains) ----
    // A[m][h] element j (lane g): col sigma = 32h + 4g + (j&3) + 16*(j>>2)
    bf16x8 A00,A01,A10,A11,A20,A21,A30,A31;
    {
        const __hip_bfloat16* Abase =
            (const __hip_bfloat16*)(SM + (wv == 0 ? OFF_G : OFF_T));
        #define LDFRAG(dst, m, h) { \
            const __hip_bfloat16* p_ = Abase + ((m)*16+lr)*MSTR + 32*(h) + 4*g; \
            bf16x4 lo_ = *(const bf16x4*)(p_); \
            bf16x4 hi_ = *(const bf16x4*)(p_ + 16); \
            dst[0]=lo_[0]; dst[1]=lo_[1]; dst[2]=lo_[2]; dst[3]=lo_[3]; \
            dst[4]=hi_[0]; dst[5]=hi_[1]; dst[6]=hi_[2]; dst[7]=hi_[3]; \
        }
        LDFRAG(A00,0,0); LDFRAG(A01,0,1); LDFRAG(A10,1,0); LDFRAG(A11,1,1);
        LDFRAG(A20,2,0); LDFRAG(A21,2,1); LDFRAG(A30,3,0); LDFRAG(A31,3,1);
        #undef LDFRAG
    }

    // ---- phase 3: ballot-pack y into LDS words (32 rows) ----
    unsigned long long* yball = (unsigned long long*)(SM + OFF_YB);
    #pragma unroll
    for (int q = 0; q < 16; q++) {
        const int row = wv*16 + q;
        const int* yr = y + (size_t)(R0 + row) * TLEN;
        #pragma unroll
        for (int w = 0; w < 16; w++) {
            const unsigned long long bal = __ballot(yr[w*64 + lane] != 0);
            if (lane == 0) yball[row*16 + w] = bal;
        }
    }
    __syncthreads();

    // ---- phase 4: per-lane bit-stream registers for BOTH chains ----
    // stream bit s: fwd -> y[s+1] (s=0..510); bwd -> y[1022-s]
    unsigned long long BSX[8], BSY[8];
    int initX, initY;
    {
        unsigned long long rawX[8], rawY[8];
        if (wv == 0) {
            #pragma unroll
            for (int w = 0; w < 8; w++) {
                rawX[w] = yball[lr*16 + w];
                rawY[w] = yball[(16+lr)*16 + w];
            }
        } else {
            #pragma unroll
            for (int w = 0; w < 8; w++) {
                rawX[w] = __brevll(yball[lr*16 + (15-w)]);
                rawY[w] = __brevll(yball[(16+lr)*16 + (15-w)]);
            }
        }
        initX = (int)(rawX[0] & 1ull);        // fwd: y[0]; bwd: y[1023]
        initY = (int)(rawY[0] & 1ull);
        #pragma unroll
        for (int w = 0; w < 7; w++) {
            BSX[w] = (rawX[w] >> 1) | (rawX[w+1] << 63);
            BSY[w] = (rawY[w] >> 1) | (rawY[w+1] << 63);
        }
        BSX[7] = rawX[7] >> 1;
        BSY[7] = rawY[7] >> 1;
    }

    const f32x4 e0_0 = *(const f32x4*)(pE +       0 + 4*g);
    const f32x4 e0_1 = *(const f32x4*)(pE +      16 + 4*g);
    const f32x4 e0_2 = *(const f32x4*)(pE +      32 + 4*g);
    const f32x4 e0_3 = *(const f32x4*)(pE +      48 + 4*g);
    const f32x4 e1_0 = *(const f32x4*)(pE + 64 +  0 + 4*g);
    const f32x4 e1_1 = *(const f32x4*)(pE + 64 + 16 + 4*g);
    const f32x4 e1_2 = *(const f32x4*)(pE + 64 + 32 + 4*g);
    const f32x4 e1_3 = *(const f32x4*)(pE + 64 + 48 + 4*g);

    f32x4 d0X,d1X,d2X,d3X, d0Y,d1Y,d2Y,d3Y;
    if (wv == 0) {                        // alpha_0 = piv ⊙ e_{y0}
        const f32x4 p0 = *(const f32x4*)(piv +  0 + 4*g);
        const f32x4 p1 = *(const f32x4*)(piv + 16 + 4*g);
        const f32x4 p2 = *(const f32x4*)(piv + 32 + 4*g);
        const f32x4 p3 = *(const f32x4*)(piv + 48 + 4*g);
        d0X = p0 * (initX ? e1_0 : e0_0);
        d1X = p1 * (initX ? e1_1 : e0_1);
        d2X = p2 * (initX ? e1_2 : e0_2);
        d3X = p3 * (initX ? e1_3 : e0_3);
        d0Y = p0 * (initY ? e1_0 : e0_0);
        d1Y = p1 * (initY ? e1_1 : e0_1);
        d2Y = p2 * (initY ? e1_2 : e0_2);
        d3Y = p3 * (initY ? e1_3 : e0_3);
    } else {                              // gamma_1023 = e_{y1023}
        d0X = initX ? e1_0 : e0_0;
        d1X = initX ? e1_1 : e0_1;
        d2X = initX ? e1_2 : e0_2;
        d3X = initX ? e1_3 : e0_3;
        d0Y = initY ? e1_0 : e0_0;
        d1Y = initY ? e1_1 : e0_1;
        d2Y = initY ? e1_2 : e0_2;
        d3Y = initY ? e1_3 : e0_3;
    }

    // ---- main loop: 511 register-only steps, 2 chains interleaved ----
    f32x4 t0X,t1X,t2X,t3X, t0Y,t1Y,t2Y,t3Y;
    #define MATVEC(S) { \
        u32x4 w1_, w2_; \
        w1_[0] = packpair(d0##S.x, d0##S.y);  w1_[1] = packpair(d0##S.z, d0##S.w); \
        w1_[2] = packpair(d1##S.x, d1##S.y);  w1_[3] = packpair(d1##S.z, d1##S.w); \
        w2_[0] = packpair(d2##S.x, d2##S.y);  w2_[1] = packpair(d2##S.z, d2##S.w); \
        w2_[2] = packpair(d3##S.x, d3##S.y);  w2_[3] = packpair(d3##S.z, d3##S.w); \
        const bf16x8 b1_ = __builtin_bit_cast(bf16x8, w1_); \
        const bf16x8 b2_ = __builtin_bit_cast(bf16x8, w2_); \
        t0##S = MFMA(A00, b1_, zero); t1##S = MFMA(A10, b1_, zero); \
        t2##S = MFMA(A20, b1_, zero); t3##S = MFMA(A30, b1_, zero); \
        t0##S = MFMA(A01, b2_, t0##S);   t1##S = MFMA(A11, b2_, t1##S); \
        t2##S = MFMA(A21, b2_, t2##S);   t3##S = MFMA(A31, b2_, t3##S); \
    }
    #define RENORM(S) { \
        float S_ = t0##S.x+t0##S.y+t0##S.z+t0##S.w + t1##S.x+t1##S.y+t1##S.z+t1##S.w \
                 + t2##S.x+t2##S.y+t2##S.z+t2##S.w + t3##S.x+t3##S.y+t3##S.z+t3##S.w; \
        S_ += __shfl_xor(S_, 16); \
        S_ += __shfl_xor(S_, 32); \
        lacc##S += __logf(S_); \
        const float rn_ = __builtin_amdgcn_rcpf(S_); \
        t0##S *= rn_; t1##S *= rn_; t2##S *= rn_; t3##S *= rn_; \
    }
    #define EMIT(S) { \
        const bool yb_ = (cur##S & 1ull) != 0; \
        cur##S >>= 1; \
        d0##S = t0##S * (yb_ ? e1_0 : e0_0); \
        d1##S = t1##S * (yb_ ? e1_1 : e0_1); \
        d2##S = t2##S * (yb_ ? e1_2 : e0_2); \
        d3##S = t3##S * (yb_ ? e1_3 : e0_3); \
    }

    float laccX = 0.f, laccY = 0.f;
    #pragma unroll
    for (int blk = 0; blk < 8; blk++) {
        unsigned long long curX = BSX[blk];
        unsigned long long curY = BSY[blk];
        const int n = (blk == 7) ? 63 : 64;     // 7*64 + 63 = 511 steps
        for (int i = 0; i < n; i++) {
            MATVEC(X);
            MATVEC(Y);
            if ((i & 15) == 15) {               // renorm every 16 steps
                RENORM(X);
                RENORM(Y);
            }
            EMIT(X);
            EMIT(Y);
        }
    }

    // ---- fwd: one bare matvec per chain (no emission) -> abar_512 ----
    if (wv == 0) {
        MATVEC(X);
        d0X = t0X; d1X = t1X; d2X = t2X; d3X = t3X;
        MATVEC(Y);
        d0Y = t0Y; d1Y = t1Y; d2Y = t2Y; d3Y = t3Y;
    }
    #undef MATVEC
    #undef RENORM
    #undef EMIT

    // ---- combine: logP = laccF + laccB + log(abar_512 . gamma_512) ----
    if (wv == 1) {
        float* CB = (float*)(SM + OFF_CMB);
        *(f32x4*)(CB + lr*CSTR +  0 + 4*g) = d0X;
        *(f32x4*)(CB + lr*CSTR + 16 + 4*g) = d1X;
        *(f32x4*)(CB + lr*CSTR + 32 + 4*g) = d2X;
        *(f32x4*)(CB + lr*CSTR + 48 + 4*g) = d3X;
        *(f32x4*)(CB + (16+lr)*CSTR +  0 + 4*g) = d0Y;
        *(f32x4*)(CB + (16+lr)*CSTR + 16 + 4*g) = d1Y;
        *(f32x4*)(CB + (16+lr)*CSTR + 32 + 4*g) = d2Y;
        *(f32x4*)(CB + (16+lr)*CSTR + 48 + 4*g) = d3Y;
        float* LB = (float*)(SM + OFF_LACB);
        if (lane < 16)      LB[lane]      = laccX;   // g==0 lanes: chain X
        else if (lane < 32) LB[16 + lr]   = laccY;   // g==1 lanes: chain Y
    }
    __syncthreads();
    if (wv == 0) {
        const float* CB = (const float*)(SM + OFF_CMB);
        const float* LB = (const float*)(SM + OFF_LACB);
        const f32x4 q0 = *(const f32x4*)(CB + lr*CSTR +  0 + 4*g);
        const f32x4 q1 = *(const f32x4*)(CB + lr*CSTR + 16 + 4*g);
        const f32x4 q2 = *(const f32x4*)(CB + lr*CSTR + 32 + 4*g);
        const f32x4 q3 = *(const f32x4*)(CB + lr*CSTR + 48 + 4*g);
        float dotX = d0X.x*q0.x + d0X.y*q0.y + d0X.z*q0.z + d0X.w*q0.w
                   + d1X.x*q1.x + d1X.y*q1.y + d1X.z*q1.z + d1X.w*q1.w
                   + d2X.x*q2.x + d2X.y*q2.y + d2X.z*q2.z + d2X.w*q2.w
                   + d3X.x*q3.x + d3X.y*q3.y + d3X.z*q3.z + d3X.w*q3.w;
        const f32x4 r0 = *(const f32x4*)(CB + (16+lr)*CSTR +  0 + 4*g);
        const f32x4 r1 = *(const f32x4*)(CB + (16+lr)*CSTR + 16 + 4*g);
        const f32x4 r2 = *(const f32x4*)(CB + (16+lr)*CSTR + 32 + 4*g);
        const f32x4 r3 = *(const f32x4*)(CB + (16+lr)*CSTR + 48 + 4*g);
        float dotY = d0Y.x*r0.x + d0Y.y*r0.y + d0Y.z*r0.z + d0Y.w*r0.w
                   + d1Y.x*r1.x + d1Y.y*r1.y + d1Y.z*r1.z + d1Y.w*r1.w
                   + d2Y.x*r2.x + d2Y.y*r2.y + d2Y.z*r2.z + d2Y.w*r2.w
                   + d3Y.x*r3.x + d3Y.y*r3.y + d3Y.z*r3.z + d3Y.w*r3.w;
        dotX += __shfl_xor(dotX, 16);
        dotX += __shfl_xor(dotX, 32);
        dotY += __shfl_xor(dotY, 16);
        dotY += __shfl_xor(dotY, 32);
        const float lpX = laccX + LB[lr]      + __logf(dotX);
        const float lpY = laccY + LB[16 + lr] + __logf(dotY);
        float lp = lpX + lpY;
        if (g == 0) {                      // lanes 0..15: reduce over 16 cols
            lp += __shfl_xor(lp, 1);
            lp += __shfl_xor(lp, 2);
            lp += __shfl_xor(lp, 4);
            lp += __shfl_xor(lp, 8);
            if (lr == 0) atomicAdd(out, lp * (1.0f / BATCH));
        }
    }
}

// ---------------------------------------------------------------------------
extern "C" void kernel_launch(void* const* d_in, const int* in_sizes, int n_in,
                              void* d_out, int out_size, void* d_ws, size_t ws_size,
                              hipStream_t stream) {
    const int*   y  = (const int*)  d_in[0];
    const float* T  = (const float*)d_in[1];
    const float* E  = (const float*)d_in[2];
    const float* Pi = (const float*)d_in[3];
    float* out = (float*)d_out;
    (void)d_ws; (void)ws_size; (void)in_sizes; (void)n_in; (void)out_size;

    hipMemsetAsync(out, 0, sizeof(float), stream);
    hipLaunchKernelGGL(hmm_fb, dim3(BATCH/32), dim3(128), 0, stream,
                       y, T, E, Pi, out);
}

// Round 5
// 222.163 us; speedup vs baseline: 1.5044x; 1.5044x over previous
//
#include <hip/hip_runtime.h>
#include <hip/hip_bf16.h>
#include <stdint.h>

#define BATCH 4096
#define TLEN  1024
#define MSTR  72      // LDS stride (bf16 elems) for matrices; 144B keeps 16B alignment
#define MATB  9216    // one 64xMSTR bf16 matrix, bytes
#define CSTR  68      // combine buffer stride (f32)

// ---- LDS layout (bytes) ----
#define OFF_SP0   0        // S_b = Tsoft * D(pE_b)  (plain)      [fwd family]
#define OFF_SP1   9216
#define OFF_ST0   18432    // S_b transposed
#define OFF_ST1   27648
#define OFF_ZP0   36864    // Z_b = D(pE_b) * Tsoft  (plain)      [bwd family]
#define OFF_ZP1   46080
#define OFF_ZT0   55296    // Z_b transposed
#define OFF_ZT1   64512
#define OFF_TP    73728    // bare Tsoft plain
#define OFF_TT    82944    // bare Tsoft transposed
#define OFF_CS    92160    // per-wave candidate scratch, 2 x 9216
#define OFF_PE    110592   // float pE[2][64]
#define OFF_PIV   111104   // float piv[64]
#define OFF_YB    111360   // u64 yball[16][16] = 2048
#define OFF_CMB   113408   // float gamma[16][CSTR] = 4352
#define OFF_LACB  117760   // float laccB[16]
#define SMEM_SZ   117824

typedef short        bf16x4 __attribute__((ext_vector_type(4)));
typedef short        bf16x8 __attribute__((ext_vector_type(8)));
typedef float        f32x4  __attribute__((ext_vector_type(4)));
typedef unsigned int u32;
typedef unsigned int u32x4  __attribute__((ext_vector_type(4)));

#define MFMA(a,b,c) __builtin_amdgcn_mfma_f32_16x16x32_bf16(a,b,c,0,0,0)

// Pack two f32 -> one u32 of 2x bf16 (RNE), pure register ops (SROA-safe).
static __device__ __forceinline__ u32 packpair(float lo, float hi) {
    const u32 l = (u32)__builtin_bit_cast(unsigned short, __float2bfloat16(lo));
    const u32 h = (u32)__builtin_bit_cast(unsigned short, __float2bfloat16(hi));
    return l | (h << 16);
}
static __device__ __forceinline__ bf16x8 packB(const f32x4 a, const f32x4 b) {
    u32x4 w;
    w[0] = packpair(a.x, a.y);  w[1] = packpair(a.z, a.w);
    w[2] = packpair(b.x, b.y);  w[3] = packpair(b.z, b.w);
    return __builtin_bit_cast(bf16x8, w);
}

// ---------------------------------------------------------------------------
// 256 wgs x 128 thr (2 waves). wg = 16-batch block:
//   wave0: forward alpha-chain,  pair matrices M_q = S_{q&1} * S_{q>>1}
//   wave1: backward gamma-chain, pair matrices M_q = Z_{q>>1} * Z_{q&1}
// Each pair-iteration advances TWO time steps with ONE pack->MFMA->select
// round: 32 MFMA (4 candidates x 4 tiles x 2 k-halves) + 2-bit per-column
// select (12 f32x4 cndmask). Emissions are folded into the candidate
// matrices (no EMIT in the loop). Candidates are built in the prologue by
// MFMA outer products (C = P*Q^T contract) and sigma-gathered into 32
// register A-frags. Single leftover step + fwd bare tail use bare-T frags
// (round-3 machinery). Renorm every 8 iters (16 steps). Combine in-wg.
// ---------------------------------------------------------------------------
__global__ __launch_bounds__(128, 1) void hmm_fb(
    const int* __restrict__ y, const float* __restrict__ Tmat,
    const float* __restrict__ Emat, const float* __restrict__ Pi,
    float* __restrict__ out)
{
    __shared__ __align__(16) unsigned char SM[SMEM_SZ];

    const int tid  = threadIdx.x;
    const int wv   = tid >> 6;          // 0 = fwd, 1 = bwd
    const int lane = tid & 63;
    const int lr   = lane & 15;         // batch col / matrix row-in-tile
    const int g    = lane >> 4;         // k-group
    const int R0   = blockIdx.x << 4;

    float* pE  = (float*)(SM + OFF_PE);
    float* piv = (float*)(SM + OFF_PIV);
    const f32x4 zero = {0.f, 0.f, 0.f, 0.f};

    // ---- phase 0: emission + pi softmax ----
    if (tid < 64) {
        const float e0 = Emat[tid*2+0], e1 = Emat[tid*2+1];
        const float em = fmaxf(e0, e1);
        const float p0 = __expf(e0-em), p1 = __expf(e1-em);
        const float ez = 1.0f / (p0 + p1);
        pE[tid]      = p0 * ez;
        pE[64 + tid] = p1 * ez;
        float v = Pi[tid];
        float mx = v;
        #pragma unroll
        for (int d = 1; d < 64; d <<= 1) mx = fmaxf(mx, __shfl_xor(mx, d));
        const float e = __expf(v - mx);
        float z = e;
        #pragma unroll
        for (int d = 1; d < 64; d <<= 1) z += __shfl_xor(z, d);
        piv[tid] = e / z;
    }
    __syncthreads();   // phase 1 reads pE

    // ---- phase 1: row-softmax of T -> 10 base matrices (plain+transposed) ----
    {
        const int r  = tid >> 1;          // 0..63
        const int hh = tid & 1;           // 32-col half
        float v[32];
        #pragma unroll
        for (int q = 0; q < 8; q++) {
            const float4 t4 = *(const float4*)(Tmat + r*64 + hh*32 + q*4);
            v[q*4+0]=t4.x; v[q*4+1]=t4.y; v[q*4+2]=t4.z; v[q*4+3]=t4.w;
        }
        float mx = v[0];
        #pragma unroll
        for (int k = 1; k < 32; k++) mx = fmaxf(mx, v[k]);
        mx = fmaxf(mx, __shfl_xor(mx, 1));
        float z = 0.f;
        #pragma unroll
        for (int k = 0; k < 32; k++) { v[k] = __expf(v[k]-mx); z += v[k]; }
        z += __shfl_xor(z, 1);
        const float inv = 1.0f / z;
        const float er0 = pE[r], er1 = pE[64 + r];   // row-scale for Z family
        __hip_bfloat16* Sp0 = (__hip_bfloat16*)(SM + OFF_SP0);
        __hip_bfloat16* Sp1 = (__hip_bfloat16*)(SM + OFF_SP1);
        __hip_bfloat16* St0 = (__hip_bfloat16*)(SM + OFF_ST0);
        __hip_bfloat16* St1 = (__hip_bfloat16*)(SM + OFF_ST1);
        __hip_bfloat16* Zp0 = (__hip_bfloat16*)(SM + OFF_ZP0);
        __hip_bfloat16* Zp1 = (__hip_bfloat16*)(SM + OFF_ZP1);
        __hip_bfloat16* Zt0 = (__hip_bfloat16*)(SM + OFF_ZT0);
        __hip_bfloat16* Zt1 = (__hip_bfloat16*)(SM + OFF_ZT1);
        __hip_bfloat16* Tp  = (__hip_bfloat16*)(SM + OFF_TP);
        __hip_bfloat16* Tt  = (__hip_bfloat16*)(SM + OFF_TT);
        #pragma unroll
        for (int k = 0; k < 32; k++) {
            const int j = hh*32 + k;
            const float tval = v[k] * inv;
            const __hip_bfloat16 hb  = __float2bfloat16(tval);
            const __hip_bfloat16 hs0 = __float2bfloat16(tval * pE[j]);
            const __hip_bfloat16 hs1 = __float2bfloat16(tval * pE[64 + j]);
            const __hip_bfloat16 hz0 = __float2bfloat16(er0 * tval);
            const __hip_bfloat16 hz1 = __float2bfloat16(er1 * tval);
            Sp0[r*MSTR + j] = hs0;  Sp1[r*MSTR + j] = hs1;
            St0[j*MSTR + r] = hs0;  St1[j*MSTR + r] = hs1;
            Zp0[r*MSTR + j] = hz0;  Zp1[r*MSTR + j] = hz1;
            Zt0[j*MSTR + r] = hz0;  Zt1[j*MSTR + r] = hz1;
            Tp [r*MSTR + j] = hb;   Tt [j*MSTR + r] = hb;
        }
    }
    __syncthreads();   // phase 2 reads base matrices from both waves' writes

    // ---- LDFRAG: sigma-permuted A-frag gather (round-3 proven) ----
    #define LDFRAG(dst, base, row, h) { \
        const __hip_bfloat16* p_ = (base) + (row)*MSTR + 32*(h) + 4*g; \
        bf16x4 lo_ = *(const bf16x4*)(p_); \
        bf16x4 hi_ = *(const bf16x4*)(p_ + 16); \
        dst[0]=lo_[0]; dst[1]=lo_[1]; dst[2]=lo_[2]; dst[3]=lo_[3]; \
        dst[4]=hi_[0]; dst[5]=hi_[1]; dst[6]=hi_[2]; dst[7]=hi_[3]; }

    // ---- phase 2: build 4 pair-candidates per wave via MFMA; gather frags ----
    // Contract: a-frags = rows of P, b-frags = rows of Q (same linear k map)
    //   => D(reg q', lane(g,lr), tile(xt,yb)) = (P*Q^T)[xt*16+4g+q'][yb*16+lr]
    // Stored at buf[y][x]: buf = (P*Q^T)^T.
    //   fwd: P=Sp_{q&1}, Q=St_{q>>1} => buf = (S_{q&1} S_{q>>1})^T = M_q^T  (A-src)
    //   bwd: P=Zt_{q&1}, Q=Zp_{q>>1} => buf = Z_{q>>1} Z_{q&1}     = M_q^T  (A-src)
    bf16x8 AQ[4][4][2];
    {
        const __hip_bfloat16* PB =
            (const __hip_bfloat16*)(SM + (wv ? OFF_ZT0 : OFF_SP0));
        const __hip_bfloat16* QB =
            (const __hip_bfloat16*)(SM + (wv ? OFF_ZP0 : OFF_ST0));
        __hip_bfloat16* CS = (__hip_bfloat16*)(SM + OFF_CS) + wv*(64*MSTR);
        #pragma unroll
        for (int q = 0; q < 4; q++) {
            const __hip_bfloat16* P = PB + (q & 1) * (64*MSTR);
            const __hip_bfloat16* Q = QB + (q >> 1) * (64*MSTR);
            #pragma unroll
            for (int xt = 0; xt < 4; xt++) {
                const bf16x8 a0 = *(const bf16x8*)(P + (xt*16+lr)*MSTR + g*8);
                const bf16x8 a1 = *(const bf16x8*)(P + (xt*16+lr)*MSTR + 32 + g*8);
                #pragma unroll
                for (int yb = 0; yb < 4; yb++) {
                    const bf16x8 q0 = *(const bf16x8*)(Q + (yb*16+lr)*MSTR + g*8);
                    const bf16x8 q1 = *(const bf16x8*)(Q + (yb*16+lr)*MSTR + 32 + g*8);
                    f32x4 dd = MFMA(a0, q0, zero);
                    dd = MFMA(a1, q1, dd);
                    union { __hip_bfloat16 hh4[4]; uint2 u; } pk;
                    pk.hh4[0] = __float2bfloat16(dd.x);
                    pk.hh4[1] = __float2bfloat16(dd.y);
                    pk.hh4[2] = __float2bfloat16(dd.z);
                    pk.hh4[3] = __float2bfloat16(dd.w);
                    *(uint2*)(CS + (yb*16+lr)*MSTR + xt*16 + 4*g) = pk.u;
                }
            }
            // gather this candidate's 8 sigma-frags (same-wave LDS RAW; the
            // compiler orders ds ops + lgkmcnt; per-wave scratch => no races)
            #pragma unroll
            for (int m = 0; m < 4; m++) {
                LDFRAG(AQ[q][m][0], CS, m*16+lr, 0);
                LDFRAG(AQ[q][m][1], CS, m*16+lr, 1);
            }
        }
    }

    // bare-T frags for the single step (+ fwd tail)
    bf16x8 TB[4][2];
    {
        const __hip_bfloat16* Tb =
            (const __hip_bfloat16*)(SM + (wv ? OFF_TP : OFF_TT));
        #pragma unroll
        for (int m = 0; m < 4; m++) {
            LDFRAG(TB[m][0], Tb, m*16+lr, 0);
            LDFRAG(TB[m][1], Tb, m*16+lr, 1);
        }
    }
    #undef LDFRAG

    // ---- phase 3: ballot-pack y into LDS words ----
    unsigned long long* yball = (unsigned long long*)(SM + OFF_YB);
    #pragma unroll
    for (int q = 0; q < 8; q++) {
        const int row = wv*8 + q;
        const int* yr = y + (size_t)(R0 + row) * TLEN;
        #pragma unroll
        for (int w = 0; w < 16; w++) {
            const unsigned long long bal = __ballot(yr[w*64 + lane] != 0);
            if (lane == 0) yball[row*16 + w] = bal;
        }
    }
    __syncthreads();

    // ---- phase 4: per-lane 2-bit pair streams + init/step bits ----
    // fwd: stream bit p = y[p+2]  (iter j: bit0=y[2j+2]=b1, bit1=y[2j+3]=b2)
    // bwd: stream bit p = y[1021-p] (iter j: bit0=y[1021-2j]=c1, bit1=c2)
    unsigned long long BS[8];
    int initbit, stepbit;
    {
        unsigned long long raw[9];
        if (wv == 0) {
            #pragma unroll
            for (int w = 0; w < 9; w++) raw[w] = yball[lr*16 + w];
        } else {
            #pragma unroll
            for (int w = 0; w < 9; w++) raw[w] = __brevll(yball[lr*16 + (15-w)]);
        }
        initbit = (int)(raw[0] & 1ull);          // fwd: y[0];    bwd: y[1023]
        stepbit = (int)((raw[0] >> 1) & 1ull);   // fwd: y[1];    bwd: y[1022]
        #pragma unroll
        for (int w = 0; w < 8; w++) BS[w] = (raw[w] >> 2) | (raw[w+1] << 62);
    }

    const f32x4 e0_0 = *(const f32x4*)(pE +       0 + 4*g);
    const f32x4 e0_1 = *(const f32x4*)(pE +      16 + 4*g);
    const f32x4 e0_2 = *(const f32x4*)(pE +      32 + 4*g);
    const f32x4 e0_3 = *(const f32x4*)(pE +      48 + 4*g);
    const f32x4 e1_0 = *(const f32x4*)(pE + 64 +  0 + 4*g);
    const f32x4 e1_1 = *(const f32x4*)(pE + 64 + 16 + 4*g);
    const f32x4 e1_2 = *(const f32x4*)(pE + 64 + 32 + 4*g);
    const f32x4 e1_3 = *(const f32x4*)(pE + 64 + 48 + 4*g);

    f32x4 d0, d1, d2, d3;
    if (wv == 0) {                        // alpha_0 = piv ⊙ e_{y0}
        const f32x4 p0 = *(const f32x4*)(piv +  0 + 4*g);
        const f32x4 p1 = *(const f32x4*)(piv + 16 + 4*g);
        const f32x4 p2 = *(const f32x4*)(piv + 32 + 4*g);
        const f32x4 p3 = *(const f32x4*)(piv + 48 + 4*g);
        d0 = p0 * (initbit ? e1_0 : e0_0);
        d1 = p1 * (initbit ? e1_1 : e0_1);
        d2 = p2 * (initbit ? e1_2 : e0_2);
        d3 = p3 * (initbit ? e1_3 : e0_3);
    } else {                              // gamma_1023 = e_{y1023}
        d0 = initbit ? e1_0 : e0_0;
        d1 = initbit ? e1_1 : e0_1;
        d2 = initbit ? e1_2 : e0_2;
        d3 = initbit ? e1_3 : e0_3;
    }

    // ---- single leftover step (fwd t=1, bwd t=1022): bare T + e-select ----
    {
        const bf16x8 sb1 = packB(d0, d1);
        const bf16x8 sb2 = packB(d2, d3);
        f32x4 t0 = MFMA(TB[0][0], sb1, zero);
        f32x4 t1 = MFMA(TB[1][0], sb1, zero);
        f32x4 t2 = MFMA(TB[2][0], sb1, zero);
        f32x4 t3 = MFMA(TB[3][0], sb1, zero);
        t0 = MFMA(TB[0][1], sb2, t0);
        t1 = MFMA(TB[1][1], sb2, t1);
        t2 = MFMA(TB[2][1], sb2, t2);
        t3 = MFMA(TB[3][1], sb2, t3);
        d0 = t0 * (stepbit ? e1_0 : e0_0);
        d1 = t1 * (stepbit ? e1_1 : e0_1);
        d2 = t2 * (stepbit ? e1_2 : e0_2);
        d3 = t3 * (stepbit ? e1_3 : e0_3);
    }

    // ---- main loop: 255 pair-iterations (510 steps), register-only ----
    float lacc = 0.f;
    #pragma unroll
    for (int blk = 0; blk < 8; blk++) {
        unsigned long long cur = BS[blk];
        const int n = (blk == 7) ? 31 : 32;   // 7*32 + 31 = 255 iters
        for (int i = 0; i < n; i++) {
            const bf16x8 b1 = packB(d0, d1);
            const bf16x8 b2 = packB(d2, d3);
            const int idx = (int)(cur & 3ull);
            cur >>= 2;
            f32x4 ca[4][4];
            #pragma unroll
            for (int q = 0; q < 4; q++)
                #pragma unroll
                for (int m = 0; m < 4; m++)
                    ca[q][m] = MFMA(AQ[q][m][0], b1, zero);
            #pragma unroll
            for (int q = 0; q < 4; q++)
                #pragma unroll
                for (int m = 0; m < 4; m++)
                    ca[q][m] = MFMA(AQ[q][m][1], b2, ca[q][m]);
            const bool lo = (idx & 1) != 0;
            const bool hi = (idx & 2) != 0;
            { const f32x4 v_ = lo ? ca[1][0] : ca[0][0];
              const f32x4 w_ = lo ? ca[3][0] : ca[2][0];
              d0 = hi ? w_ : v_; }
            { const f32x4 v_ = lo ? ca[1][1] : ca[0][1];
              const f32x4 w_ = lo ? ca[3][1] : ca[2][1];
              d1 = hi ? w_ : v_; }
            { const f32x4 v_ = lo ? ca[1][2] : ca[0][2];
              const f32x4 w_ = lo ? ca[3][2] : ca[2][2];
              d2 = hi ? w_ : v_; }
            { const f32x4 v_ = lo ? ca[1][3] : ca[0][3];
              const f32x4 w_ = lo ? ca[3][3] : ca[2][3];
              d3 = hi ? w_ : v_; }
            if ((i & 7) == 7) {                 // renorm every 8 iters (16 steps)
                float S = d0.x+d0.y+d0.z+d0.w + d1.x+d1.y+d1.z+d1.w
                        + d2.x+d2.y+d2.z+d2.w + d3.x+d3.y+d3.z+d3.w;
                S += __shfl_xor(S, 16);
                S += __shfl_xor(S, 32);
                lacc += __logf(S);
                const float rn = __builtin_amdgcn_rcpf(S);
                d0 *= rn; d1 *= rn; d2 *= rn; d3 *= rn;
            }
        }
    }

    // ---- fwd tail: bare matvec (no emission) -> abar_512 ----
    if (wv == 0) {
        const bf16x8 b1 = packB(d0, d1);
        const bf16x8 b2 = packB(d2, d3);
        f32x4 t0 = MFMA(TB[0][0], b1, zero);
        f32x4 t1 = MFMA(TB[1][0], b1, zero);
        f32x4 t2 = MFMA(TB[2][0], b1, zero);
        f32x4 t3 = MFMA(TB[3][0], b1, zero);
        t0 = MFMA(TB[0][1], b2, t0);
        t1 = MFMA(TB[1][1], b2, t1);
        t2 = MFMA(TB[2][1], b2, t2);
        t3 = MFMA(TB[3][1], b2, t3);
        d0 = t0; d1 = t1; d2 = t2; d3 = t3;
    }

    // ---- combine: logP = laccF + laccB + log(abar_512 . gamma_512) ----
    if (wv == 1) {
        float* CB = (float*)(SM + OFF_CMB);
        *(f32x4*)(CB + lr*CSTR +  0 + 4*g) = d0;
        *(f32x4*)(CB + lr*CSTR + 16 + 4*g) = d1;
        *(f32x4*)(CB + lr*CSTR + 32 + 4*g) = d2;
        *(f32x4*)(CB + lr*CSTR + 48 + 4*g) = d3;
        if (lane < 16) ((float*)(SM + OFF_LACB))[lane] = lacc;
    }
    __syncthreads();
    if (wv == 0) {
        const float* CB = (const float*)(SM + OFF_CMB);
        const f32x4 q0 = *(const f32x4*)(CB + lr*CSTR +  0 + 4*g);
        const f32x4 q1 = *(const f32x4*)(CB + lr*CSTR + 16 + 4*g);
        const f32x4 q2 = *(const f32x4*)(CB + lr*CSTR + 32 + 4*g);
        const f32x4 q3 = *(const f32x4*)(CB + lr*CSTR + 48 + 4*g);
        float dot = d0.x*q0.x + d0.y*q0.y + d0.z*q0.z + d0.w*q0.w
                  + d1.x*q1.x + d1.y*q1.y + d1.z*q1.z + d1.w*q1.w
                  + d2.x*q2.x + d2.y*q2.y + d2.z*q2.z + d2.w*q2.w
                  + d3.x*q3.x + d3.y*q3.y + d3.z*q3.z + d3.w*q3.w;
        dot += __shfl_xor(dot, 16);
        dot += __shfl_xor(dot, 32);
        float lp = lacc + ((const float*)(SM + OFF_LACB))[lr] + __logf(dot);
        if (g == 0) {
            lp += __shfl_xor(lp, 1);
            lp += __shfl_xor(lp, 2);
            lp += __shfl_xor(lp, 4);
            lp += __shfl_xor(lp, 8);
            if (lr == 0) atomicAdd(out, lp * (1.0f / BATCH));
        }
    }
}

// ---------------------------------------------------------------------------
extern "C" void kernel_launch(void* const* d_in, const int* in_sizes, int n_in,
                              void* d_out, int out_size, void* d_ws, size_t ws_size,
                              hipStream_t stream) {
    const int*   y  = (const int*)  d_in[0];
    const float* T  = (const float*)d_in[1];
    const float* E  = (const float*)d_in[2];
    const float* Pi = (const float*)d_in[3];
    float* out = (float*)d_out;
    (void)d_ws; (void)ws_size; (void)in_sizes; (void)n_in; (void)out_size;

    hipMemsetAsync(out, 0, sizeof(float), stream);
    hipLaunchKernelGGL(hmm_fb, dim3(BATCH/16), dim3(128), 0, stream,
                       y, T, E, Pi, out);
}

// Round 6
// 187.557 us; speedup vs baseline: 1.7820x; 1.1845x over previous
//
#include <hip/hip_runtime.h>
#include <hip/hip_bf16.h>
#include <stdint.h>

#define BATCH 4096
#define TLEN  1024
#define MSTR  72     // LDS stride (bf16 elems) for T matrices; 144B keeps b64/b128 alignment
#define CSTR  68     // combine buffer stride (f32); 272B keeps f32x4 alignment

// ---- LDS layout (bytes) ----
#define OFF_T    0        // Tsm plain [64][MSTR] bf16   (bwd A source)
#define OFF_G    9216     // Tsm^T     [64][MSTR] bf16   (fwd A source)
#define OFF_PE   18432    // float pE[2][64]
#define OFF_PIV  18944    // float piv[64]
#define OFF_YB   19200    // u64 yball[16][16] = 2048
#define OFF_CMB  21376    // float gamma[16][CSTR]
#define OFF_LACB 25728    // float laccB[16]
#define OFF_YS   25792    // u64 ybsL[2 waves][8 words][64 lanes] = 8192
#define SMEM_SZ  33984

typedef short        bf16x4 __attribute__((ext_vector_type(4)));
typedef short        bf16x8 __attribute__((ext_vector_type(8)));
typedef float        f32x4  __attribute__((ext_vector_type(4)));
typedef unsigned int u32;
typedef unsigned int u32x4  __attribute__((ext_vector_type(4)));

#define MFMA(a,b,c) __builtin_amdgcn_mfma_f32_16x16x32_bf16(a,b,c,0,0,0)

// Pack two f32 -> one u32 of 2x bf16 (RNE), pure register ops (SROA-safe).
static __device__ __forceinline__ u32 packpair(float lo, float hi) {
    const u32 l = (u32)__builtin_bit_cast(unsigned short, __float2bfloat16(lo));
    const u32 h = (u32)__builtin_bit_cast(unsigned short, __float2bfloat16(hi));
    return l | (h << 16);
}

// ---------------------------------------------------------------------------
// 256 wgs x 128 thr (2 waves). wg = 16-batch block, BOTH directions:
//   wave0: forward  alpha-chain, A = T^T (permuted k-order)
//   wave1: backward gamma-chain (gamma_t = e_t ⊙ beta_t), A = T (permuted)
// Register-only chain exactly as round 3. ROUND-6 DELTA: the main loop is
// code-size-bounded (round 3-5 post-mortem: fully-unrolled 511-step bodies
// are ~240KB of straight-line code, 7x L1I -> every instr streams from L2
// at ~14 cy/instr). Now: '#pragma unroll 1' outer loop over 32 groups with
// a 16-step unrolled body (~9KB, fits 32KB L1I, re-executed 31x) + rolled
// 15-step tail. Bit-words live in a per-lane LDS array (each lane reads
// only its own slots; no cross-lane sharing, no barrier needed).
// Renorm positions identical to round 3 (steps 15,31,...,495).
// ---------------------------------------------------------------------------
__global__ __launch_bounds__(128, 1) void hmm_fb(
    const int* __restrict__ y, const float* __restrict__ Tmat,
    const float* __restrict__ Emat, const float* __restrict__ Pi,
    float* __restrict__ out)
{
    __shared__ __align__(16) unsigned char SM[SMEM_SZ];

    const int tid  = threadIdx.x;
    const int wv   = tid >> 6;          // 0 = fwd, 1 = bwd
    const int lane = tid & 63;
    const int lr   = lane & 15;         // batch col
    const int g    = lane >> 4;         // k-group
    const int R0   = blockIdx.x << 4;

    float* pE  = (float*)(SM + OFF_PE);
    float* piv = (float*)(SM + OFF_PIV);
    const f32x4 zero = {0.f, 0.f, 0.f, 0.f};

    // ---- phase 0: emission + pi softmax ----
    if (tid < 64) {
        const float e0 = Emat[tid*2+0], e1 = Emat[tid*2+1];
        const float em = fmaxf(e0, e1);
        const float p0 = __expf(e0-em), p1 = __expf(e1-em);
        const float ez = 1.0f / (p0 + p1);
        pE[tid]      = p0 * ez;
        pE[64 + tid] = p1 * ez;
        float v = Pi[tid];
        float mx = v;
        #pragma unroll
        for (int d = 1; d < 64; d <<= 1) mx = fmaxf(mx, __shfl_xor(mx, d));
        const float e = __expf(v - mx);
        float z = e;
        #pragma unroll
        for (int d = 1; d < 64; d <<= 1) z += __shfl_xor(z, d);
        piv[tid] = e / z;
    }

    // ---- phase 1: row-softmax of T -> plain + transposed bf16 ----
    {
        const int r  = tid >> 1;          // 0..63
        const int hh = tid & 1;           // 32-col half
        float v[32];
        #pragma unroll
        for (int q = 0; q < 8; q++) {
            const float4 t4 = *(const float4*)(Tmat + r*64 + hh*32 + q*4);
            v[q*4+0]=t4.x; v[q*4+1]=t4.y; v[q*4+2]=t4.z; v[q*4+3]=t4.w;
        }
        float mx = v[0];
        #pragma unroll
        for (int k = 1; k < 32; k++) mx = fmaxf(mx, v[k]);
        mx = fmaxf(mx, __shfl_xor(mx, 1));
        float z = 0.f;
        #pragma unroll
        for (int k = 0; k < 32; k++) { v[k] = __expf(v[k]-mx); z += v[k]; }
        z += __shfl_xor(z, 1);
        const float inv = 1.0f / z;
        __hip_bfloat16* Tsm = (__hip_bfloat16*)(SM + OFF_T);
        __hip_bfloat16* Gt  = (__hip_bfloat16*)(SM + OFF_G);
        #pragma unroll
        for (int k = 0; k < 32; k++) {
            const int j = hh*32 + k;
            const __hip_bfloat16 hb = __float2bfloat16(v[k] * inv);
            Tsm[r*MSTR + j] = hb;     // Tsm[s][s']
            Gt[j*MSTR + r]  = hb;     // Gt[s'][s] = T[s][s']
        }
    }
    __syncthreads();

    // ---- phase 2: gather permuted A-fragments (register-resident) ----
    // A[m][h] element j (lane g): col sigma = 32h + 4g + (j&3) + 16*(j>>2)
    bf16x8 A00,A01,A10,A11,A20,A21,A30,A31;
    {
        const __hip_bfloat16* Abase =
            (const __hip_bfloat16*)(SM + (wv == 0 ? OFF_G : OFF_T));
        #define LDFRAG(dst, m, h) { \
            const __hip_bfloat16* p_ = Abase + ((m)*16+lr)*MSTR + 32*(h) + 4*g; \
            bf16x4 lo_ = *(const bf16x4*)(p_); \
            bf16x4 hi_ = *(const bf16x4*)(p_ + 16); \
            dst[0]=lo_[0]; dst[1]=lo_[1]; dst[2]=lo_[2]; dst[3]=lo_[3]; \
            dst[4]=hi_[0]; dst[5]=hi_[1]; dst[6]=hi_[2]; dst[7]=hi_[3]; \
        }
        LDFRAG(A00,0,0); LDFRAG(A01,0,1); LDFRAG(A10,1,0); LDFRAG(A11,1,1);
        LDFRAG(A20,2,0); LDFRAG(A21,2,1); LDFRAG(A30,3,0); LDFRAG(A31,3,1);
        #undef LDFRAG
    }

    // ---- phase 3: ballot-pack y into LDS words ----
    unsigned long long* yball = (unsigned long long*)(SM + OFF_YB);
    #pragma unroll
    for (int q = 0; q < 8; q++) {
        const int row = wv*8 + q;
        const int* yr = y + (size_t)(R0 + row) * TLEN;
        #pragma unroll
        for (int w = 0; w < 16; w++) {
            const unsigned long long bal = __ballot(yr[w*64 + lane] != 0);
            if (lane == 0) yball[row*16 + w] = bal;
        }
    }
    __syncthreads();

    // ---- phase 4: per-lane bit-streams (registers, round-3 proven), then
    //      park them in per-lane LDS slots for dynamic group indexing ----
    // stream bit s: fwd -> y[s+1] (s=0..510); bwd -> y[1022-s]
    unsigned long long* ybsL = (unsigned long long*)(SM + OFF_YS) + wv*(8*64);
    int initbit;
    {
        unsigned long long raw[8];
        if (wv == 0) {
            #pragma unroll
            for (int w = 0; w < 8; w++) raw[w] = yball[lr*16 + w];
        } else {
            #pragma unroll
            for (int w = 0; w < 8; w++) raw[w] = __brevll(yball[lr*16 + (15-w)]);
        }
        initbit = (int)(raw[0] & 1ull);           // fwd: y[0]; bwd: y[1023]
        #pragma unroll
        for (int w = 0; w < 7; w++)
            ybsL[w*64 + lane] = (raw[w] >> 1) | (raw[w+1] << 63);
        ybsL[7*64 + lane] = raw[7] >> 1;
    }
    // NOTE: each lane reads back ONLY its own ybsL slots (write->read within
    // one wave, same address); ds-op ordering via lgkmcnt. No barrier needed.

    const f32x4 e0_0 = *(const f32x4*)(pE +       0 + 4*g);
    const f32x4 e0_1 = *(const f32x4*)(pE +      16 + 4*g);
    const f32x4 e0_2 = *(const f32x4*)(pE +      32 + 4*g);
    const f32x4 e0_3 = *(const f32x4*)(pE +      48 + 4*g);
    const f32x4 e1_0 = *(const f32x4*)(pE + 64 +  0 + 4*g);
    const f32x4 e1_1 = *(const f32x4*)(pE + 64 + 16 + 4*g);
    const f32x4 e1_2 = *(const f32x4*)(pE + 64 + 32 + 4*g);
    const f32x4 e1_3 = *(const f32x4*)(pE + 64 + 48 + 4*g);

    f32x4 d0, d1, d2, d3;
    if (wv == 0) {                        // alpha_0 = piv ⊙ e_{y0}
        const f32x4 p0 = *(const f32x4*)(piv +  0 + 4*g);
        const f32x4 p1 = *(const f32x4*)(piv + 16 + 4*g);
        const f32x4 p2 = *(const f32x4*)(piv + 32 + 4*g);
        const f32x4 p3 = *(const f32x4*)(piv + 48 + 4*g);
        d0 = p0 * (initbit ? e1_0 : e0_0);
        d1 = p1 * (initbit ? e1_1 : e0_1);
        d2 = p2 * (initbit ? e1_2 : e0_2);
        d3 = p3 * (initbit ? e1_3 : e0_3);
    } else {                              // gamma_1023 = e_{y1023}
        d0 = initbit ? e1_0 : e0_0;
        d1 = initbit ? e1_1 : e0_1;
        d2 = initbit ? e1_2 : e0_2;
        d3 = initbit ? e1_3 : e0_3;
    }

    // ---- main loop: 511 register-only steps, code-size-bounded ----
    f32x4 t0, t1, t2, t3;
    #define DO_MM() { \
        u32x4 w1_, w2_; \
        w1_[0] = packpair(d0.x, d0.y);  w1_[1] = packpair(d0.z, d0.w); \
        w1_[2] = packpair(d1.x, d1.y);  w1_[3] = packpair(d1.z, d1.w); \
        w2_[0] = packpair(d2.x, d2.y);  w2_[1] = packpair(d2.z, d2.w); \
        w2_[2] = packpair(d3.x, d3.y);  w2_[3] = packpair(d3.z, d3.w); \
        const bf16x8 b1 = __builtin_bit_cast(bf16x8, w1_); \
        const bf16x8 b2 = __builtin_bit_cast(bf16x8, w2_); \
        t0 = MFMA(A00, b1, zero); t1 = MFMA(A10, b1, zero); \
        t2 = MFMA(A20, b1, zero); t3 = MFMA(A30, b1, zero); \
        t0 = MFMA(A01, b2, t0);   t1 = MFMA(A11, b2, t1); \
        t2 = MFMA(A21, b2, t2);   t3 = MFMA(A31, b2, t3); \
    }
    #define EMIT_BIT(cond) { \
        const bool yb_ = (cond); \
        d0 = t0 * (yb_ ? e1_0 : e0_0); \
        d1 = t1 * (yb_ ? e1_1 : e0_1); \
        d2 = t2 * (yb_ ? e1_2 : e0_2); \
        d3 = t3 * (yb_ ? e1_3 : e0_3); \
    }

    float lacc = 0.f;
    // 31 groups x 16 steps = steps 0..495; renorm at step 15 of each group.
    #pragma unroll 1
    for (int grp = 0; grp < 31; ++grp) {
        const unsigned long long cw = ybsL[((grp >> 2) << 6) + lane];
        const u32 bits = (u32)(cw >> ((grp & 3) << 4));
        #pragma unroll
        for (int i = 0; i < 16; ++i) {
            DO_MM();
            if (i == 15) {                      // renorm every 16 steps
                float S = t0.x+t0.y+t0.z+t0.w + t1.x+t1.y+t1.z+t1.w
                        + t2.x+t2.y+t2.z+t2.w + t3.x+t3.y+t3.z+t3.w;
                S += __shfl_xor(S, 16);
                S += __shfl_xor(S, 32);
                lacc += __logf(S);
                const float rn = __builtin_amdgcn_rcpf(S);
                t0 *= rn; t1 *= rn; t2 *= rn; t3 *= rn;
            }
            EMIT_BIT(((bits >> i) & 1u) != 0u);
        }
    }
    // tail: steps 496..510 (stream bits 48..62 of word 7), rolled
    {
        u32 bits = (u32)(ybsL[(7 << 6) + lane] >> 48);
        #pragma unroll 1
        for (int i = 0; i < 15; ++i) {
            DO_MM();
            EMIT_BIT((bits & 1u) != 0u);
            bits >>= 1;
        }
    }

    // ---- fwd: one bare matvec (no emission) -> abar_512 ----
    if (wv == 0) {
        DO_MM();
        d0 = t0; d1 = t1; d2 = t2; d3 = t3;
    }
    #undef DO_MM
    #undef EMIT_BIT

    // ---- combine: logP = laccF + laccB + log(abar_512 . gamma_512) ----
    if (wv == 1) {
        float* CB = (float*)(SM + OFF_CMB);
        *(f32x4*)(CB + lr*CSTR +  0 + 4*g) = d0;
        *(f32x4*)(CB + lr*CSTR + 16 + 4*g) = d1;
        *(f32x4*)(CB + lr*CSTR + 32 + 4*g) = d2;
        *(f32x4*)(CB + lr*CSTR + 48 + 4*g) = d3;
        if (lane < 16) ((float*)(SM + OFF_LACB))[lane] = lacc;
    }
    __syncthreads();
    if (wv == 0) {
        const float* CB = (const float*)(SM + OFF_CMB);
        const f32x4 q0 = *(const f32x4*)(CB + lr*CSTR +  0 + 4*g);
        const f32x4 q1 = *(const f32x4*)(CB + lr*CSTR + 16 + 4*g);
        const f32x4 q2 = *(const f32x4*)(CB + lr*CSTR + 32 + 4*g);
        const f32x4 q3 = *(const f32x4*)(CB + lr*CSTR + 48 + 4*g);
        float dot = d0.x*q0.x + d0.y*q0.y + d0.z*q0.z + d0.w*q0.w
                  + d1.x*q1.x + d1.y*q1.y + d1.z*q1.z + d1.w*q1.w
                  + d2.x*q2.x + d2.y*q2.y + d2.z*q2.z + d2.w*q2.w
                  + d3.x*q3.x + d3.y*q3.y + d3.z*q3.z + d3.w*q3.w;
        dot += __shfl_xor(dot, 16);
        dot += __shfl_xor(dot, 32);
        float lp = lacc + ((const float*)(SM + OFF_LACB))[lr] + __logf(dot);
        if (g == 0) {                      // lanes 0..15: reduce over batch
            lp += __shfl_xor(lp, 1);
            lp += __shfl_xor(lp, 2);
            lp += __shfl_xor(lp, 4);
            lp += __shfl_xor(lp, 8);
            if (lr == 0) atomicAdd(out, lp * (1.0f / BATCH));
        }
    }
}

// ---------------------------------------------------------------------------
extern "C" void kernel_launch(void* const* d_in, const int* in_sizes, int n_in,
                              void* d_out, int out_size, void* d_ws, size_t ws_size,
                              hipStream_t stream) {
    const int*   y  = (const int*)  d_in[0];
    const float* T  = (const float*)d_in[1];
    const float* E  = (const float*)d_in[2];
    const float* Pi = (const float*)d_in[3];
    float* out = (float*)d_out;
    (void)d_ws; (void)ws_size; (void)in_sizes; (void)n_in; (void)out_size;

    hipMemsetAsync(out, 0, sizeof(float), stream);
    hipLaunchKernelGGL(hmm_fb, dim3(BATCH/16), dim3(128), 0, stream,
                       y, T, E, Pi, out);
}

// Round 7
// 171.609 us; speedup vs baseline: 1.9476x; 1.0929x over previous
//
#include <hip/hip_runtime.h>
#include <hip/hip_bf16.h>
#include <stdint.h>

#define BATCH 4096
#define TLEN  1024
#define MSTR  72     // LDS stride (bf16 elems) for T matrices; 144B keeps b64/b128 alignment
#define CSTR  68     // combine buffer stride (f32); 272B keeps f32x4 alignment

// ---- LDS layout (bytes) ----
#define OFF_T    0        // Tsm plain [64][MSTR] bf16   (bwd A source)
#define OFF_G    9216     // Tsm^T     [64][MSTR] bf16   (fwd A source)
#define OFF_PE   18432    // float pE[2][64]
#define OFF_PIV  18944    // float piv[64]
#define OFF_YB   19200    // u64 yball[16][16] = 2048
#define OFF_CMB  21376    // float gamma[16][CSTR]
#define OFF_LACB 25728    // float laccB[16]
#define OFF_YS   25792    // u64 ybsL[2 waves][8 words][64 lanes] = 8192
#define SMEM_SZ  33984

typedef short        bf16x4 __attribute__((ext_vector_type(4)));
typedef short        bf16x8 __attribute__((ext_vector_type(8)));
typedef float        f32x4  __attribute__((ext_vector_type(4)));
typedef unsigned int u32;
typedef unsigned int u32x4  __attribute__((ext_vector_type(4)));

#define MFMA(a,b,c) __builtin_amdgcn_mfma_f32_16x16x32_bf16(a,b,c,0,0,0)

// ROUND-7 DELTA (the only change vs round 6): hardware packed conversion.
// HIP's __float2bfloat16 expands to ~6 VALU ops of software RNE; 16 of them
// per step were ~60% of all VALU issue (round-6 post-mortem). One
// v_cvt_pk_bf16_f32 does both halves: D[15:0]=bf16(S0), D[31:16]=bf16(S1),
// RNE — bit-identical byte order and rounding to the software packpair.
// Early-clobber on the output (the hygiene fix vs round 2's attempt).
static __device__ __forceinline__ u32 packpair(float lo, float hi) {
    u32 r;
    asm("v_cvt_pk_bf16_f32 %0, %1, %2" : "=&v"(r) : "v"(lo), "v"(hi));
    return r;
}

// ---------------------------------------------------------------------------
// 256 wgs x 128 thr (2 waves). wg = 16-batch block, BOTH directions:
//   wave0: forward  alpha-chain, A = T^T (permuted k-order)
//   wave1: backward gamma-chain (gamma_t = e_t ⊙ beta_t), A = T (permuted)
// Register-only chain (round-3 proven): MFMA D-fragment (rows = states
// m*16+4g+r, col = lr) repacked directly as next step's B-fragment;
// A-frags gathered once with k-slot permutation sigma(h,g,j)=32h+4g+(j&3)+16(j>>2).
// Main loop code-size-bounded (round-6 proven): '#pragma unroll 1' outer loop,
// 16-step unrolled body (fits L1I), per-lane LDS bit-words.
// Renorm every 16 steps. Combine in-wg; no workspace.
// ---------------------------------------------------------------------------
__global__ __launch_bounds__(128, 1) void hmm_fb(
    const int* __restrict__ y, const float* __restrict__ Tmat,
    const float* __restrict__ Emat, const float* __restrict__ Pi,
    float* __restrict__ out)
{
    __shared__ __align__(16) unsigned char SM[SMEM_SZ];

    const int tid  = threadIdx.x;
    const int wv   = tid >> 6;          // 0 = fwd, 1 = bwd
    const int lane = tid & 63;
    const int lr   = lane & 15;         // batch col
    const int g    = lane >> 4;         // k-group
    const int R0   = blockIdx.x << 4;

    float* pE  = (float*)(SM + OFF_PE);
    float* piv = (float*)(SM + OFF_PIV);
    const f32x4 zero = {0.f, 0.f, 0.f, 0.f};

    // ---- phase 0: emission + pi softmax ----
    if (tid < 64) {
        const float e0 = Emat[tid*2+0], e1 = Emat[tid*2+1];
        const float em = fmaxf(e0, e1);
        const float p0 = __expf(e0-em), p1 = __expf(e1-em);
        const float ez = 1.0f / (p0 + p1);
        pE[tid]      = p0 * ez;
        pE[64 + tid] = p1 * ez;
        float v = Pi[tid];
        float mx = v;
        #pragma unroll
        for (int d = 1; d < 64; d <<= 1) mx = fmaxf(mx, __shfl_xor(mx, d));
        const float e = __expf(v - mx);
        float z = e;
        #pragma unroll
        for (int d = 1; d < 64; d <<= 1) z += __shfl_xor(z, d);
        piv[tid] = e / z;
    }

    // ---- phase 1: row-softmax of T -> plain + transposed bf16 ----
    {
        const int r  = tid >> 1;          // 0..63
        const int hh = tid & 1;           // 32-col half
        float v[32];
        #pragma unroll
        for (int q = 0; q < 8; q++) {
            const float4 t4 = *(const float4*)(Tmat + r*64 + hh*32 + q*4);
            v[q*4+0]=t4.x; v[q*4+1]=t4.y; v[q*4+2]=t4.z; v[q*4+3]=t4.w;
        }
        float mx = v[0];
        #pragma unroll
        for (int k = 1; k < 32; k++) mx = fmaxf(mx, v[k]);
        mx = fmaxf(mx, __shfl_xor(mx, 1));
        float z = 0.f;
        #pragma unroll
        for (int k = 0; k < 32; k++) { v[k] = __expf(v[k]-mx); z += v[k]; }
        z += __shfl_xor(z, 1);
        const float inv = 1.0f / z;
        __hip_bfloat16* Tsm = (__hip_bfloat16*)(SM + OFF_T);
        __hip_bfloat16* Gt  = (__hip_bfloat16*)(SM + OFF_G);
        #pragma unroll
        for (int k = 0; k < 32; k++) {
            const int j = hh*32 + k;
            const __hip_bfloat16 hb = __float2bfloat16(v[k] * inv);
            Tsm[r*MSTR + j] = hb;     // Tsm[s][s']
            Gt[j*MSTR + r]  = hb;     // Gt[s'][s] = T[s][s']
        }
    }
    __syncthreads();

    // ---- phase 2: gather permuted A-fragments (register-resident) ----
    // A[m][h] element j (lane g): col sigma = 32h + 4g + (j&3) + 16*(j>>2)
    bf16x8 A00,A01,A10,A11,A20,A21,A30,A31;
    {
        const __hip_bfloat16* Abase =
            (const __hip_bfloat16*)(SM + (wv == 0 ? OFF_G : OFF_T));
        #define LDFRAG(dst, m, h) { \
            const __hip_bfloat16* p_ = Abase + ((m)*16+lr)*MSTR + 32*(h) + 4*g; \
            bf16x4 lo_ = *(const bf16x4*)(p_); \
            bf16x4 hi_ = *(const bf16x4*)(p_ + 16); \
            dst[0]=lo_[0]; dst[1]=lo_[1]; dst[2]=lo_[2]; dst[3]=lo_[3]; \
            dst[4]=hi_[0]; dst[5]=hi_[1]; dst[6]=hi_[2]; dst[7]=hi_[3]; \
        }
        LDFRAG(A00,0,0); LDFRAG(A01,0,1); LDFRAG(A10,1,0); LDFRAG(A11,1,1);
        LDFRAG(A20,2,0); LDFRAG(A21,2,1); LDFRAG(A30,3,0); LDFRAG(A31,3,1);
        #undef LDFRAG
    }

    // ---- phase 3: ballot-pack y into LDS words ----
    unsigned long long* yball = (unsigned long long*)(SM + OFF_YB);
    #pragma unroll
    for (int q = 0; q < 8; q++) {
        const int row = wv*8 + q;
        const int* yr = y + (size_t)(R0 + row) * TLEN;
        #pragma unroll
        for (int w = 0; w < 16; w++) {
            const unsigned long long bal = __ballot(yr[w*64 + lane] != 0);
            if (lane == 0) yball[row*16 + w] = bal;
        }
    }
    __syncthreads();

    // ---- phase 4: per-lane bit-streams -> per-lane LDS slots ----
    // stream bit s: fwd -> y[s+1] (s=0..510); bwd -> y[1022-s]
    unsigned long long* ybsL = (unsigned long long*)(SM + OFF_YS) + wv*(8*64);
    int initbit;
    {
        unsigned long long raw[8];
        if (wv == 0) {
            #pragma unroll
            for (int w = 0; w < 8; w++) raw[w] = yball[lr*16 + w];
        } else {
            #pragma unroll
            for (int w = 0; w < 8; w++) raw[w] = __brevll(yball[lr*16 + (15-w)]);
        }
        initbit = (int)(raw[0] & 1ull);           // fwd: y[0]; bwd: y[1023]
        #pragma unroll
        for (int w = 0; w < 7; w++)
            ybsL[w*64 + lane] = (raw[w] >> 1) | (raw[w+1] << 63);
        ybsL[7*64 + lane] = raw[7] >> 1;
    }
    // Each lane reads back ONLY its own ybsL slots (same-wave write->read,
    // same address); ds-op ordering via lgkmcnt. No barrier needed.

    const f32x4 e0_0 = *(const f32x4*)(pE +       0 + 4*g);
    const f32x4 e0_1 = *(const f32x4*)(pE +      16 + 4*g);
    const f32x4 e0_2 = *(const f32x4*)(pE +      32 + 4*g);
    const f32x4 e0_3 = *(const f32x4*)(pE +      48 + 4*g);
    const f32x4 e1_0 = *(const f32x4*)(pE + 64 +  0 + 4*g);
    const f32x4 e1_1 = *(const f32x4*)(pE + 64 + 16 + 4*g);
    const f32x4 e1_2 = *(const f32x4*)(pE + 64 + 32 + 4*g);
    const f32x4 e1_3 = *(const f32x4*)(pE + 64 + 48 + 4*g);

    f32x4 d0, d1, d2, d3;
    if (wv == 0) {                        // alpha_0 = piv ⊙ e_{y0}
        const f32x4 p0 = *(const f32x4*)(piv +  0 + 4*g);
        const f32x4 p1 = *(const f32x4*)(piv + 16 + 4*g);
        const f32x4 p2 = *(const f32x4*)(piv + 32 + 4*g);
        const f32x4 p3 = *(const f32x4*)(piv + 48 + 4*g);
        d0 = p0 * (initbit ? e1_0 : e0_0);
        d1 = p1 * (initbit ? e1_1 : e0_1);
        d2 = p2 * (initbit ? e1_2 : e0_2);
        d3 = p3 * (initbit ? e1_3 : e0_3);
    } else {                              // gamma_1023 = e_{y1023}
        d0 = initbit ? e1_0 : e0_0;
        d1 = initbit ? e1_1 : e0_1;
        d2 = initbit ? e1_2 : e0_2;
        d3 = initbit ? e1_3 : e0_3;
    }

    // ---- main loop: 511 register-only steps, code-size-bounded ----
    f32x4 t0, t1, t2, t3;
    #define DO_MM() { \
        u32x4 w1_, w2_; \
        w1_[0] = packpair(d0.x, d0.y);  w1_[1] = packpair(d0.z, d0.w); \
        w1_[2] = packpair(d1.x, d1.y);  w1_[3] = packpair(d1.z, d1.w); \
        w2_[0] = packpair(d2.x, d2.y);  w2_[1] = packpair(d2.z, d2.w); \
        w2_[2] = packpair(d3.x, d3.y);  w2_[3] = packpair(d3.z, d3.w); \
        const bf16x8 b1 = __builtin_bit_cast(bf16x8, w1_); \
        const bf16x8 b2 = __builtin_bit_cast(bf16x8, w2_); \
        t0 = MFMA(A00, b1, zero); t1 = MFMA(A10, b1, zero); \
        t2 = MFMA(A20, b1, zero); t3 = MFMA(A30, b1, zero); \
        t0 = MFMA(A01, b2, t0);   t1 = MFMA(A11, b2, t1); \
        t2 = MFMA(A21, b2, t2);   t3 = MFMA(A31, b2, t3); \
    }
    #define EMIT_BIT(cond) { \
        const bool yb_ = (cond); \
        d0 = t0 * (yb_ ? e1_0 : e0_0); \
        d1 = t1 * (yb_ ? e1_1 : e0_1); \
        d2 = t2 * (yb_ ? e1_2 : e0_2); \
        d3 = t3 * (yb_ ? e1_3 : e0_3); \
    }

    float lacc = 0.f;
    // 31 groups x 16 steps = steps 0..495; renorm at step 15 of each group.
    #pragma unroll 1
    for (int grp = 0; grp < 31; ++grp) {
        const unsigned long long cw = ybsL[((grp >> 2) << 6) + lane];
        const u32 bits = (u32)(cw >> ((grp & 3) << 4));
        #pragma unroll
        for (int i = 0; i < 16; ++i) {
            DO_MM();
            if (i == 15) {                      // renorm every 16 steps
                float S = t0.x+t0.y+t0.z+t0.w + t1.x+t1.y+t1.z+t1.w
                        + t2.x+t2.y+t2.z+t2.w + t3.x+t3.y+t3.z+t3.w;
                S += __shfl_xor(S, 16);
                S += __shfl_xor(S, 32);
                lacc += __logf(S);
                const float rn = __builtin_amdgcn_rcpf(S);
                t0 *= rn; t1 *= rn; t2 *= rn; t3 *= rn;
            }
            EMIT_BIT(((bits >> i) & 1u) != 0u);
        }
    }
    // tail: steps 496..510 (stream bits 48..62 of word 7), rolled
    {
        u32 bits = (u32)(ybsL[(7 << 6) + lane] >> 48);
        #pragma unroll 1
        for (int i = 0; i < 15; ++i) {
            DO_MM();
            EMIT_BIT((bits & 1u) != 0u);
            bits >>= 1;
        }
    }

    // ---- fwd: one bare matvec (no emission) -> abar_512 ----
    if (wv == 0) {
        DO_MM();
        d0 = t0; d1 = t1; d2 = t2; d3 = t3;
    }
    #undef DO_MM
    #undef EMIT_BIT

    // ---- combine: logP = laccF + laccB + log(abar_512 . gamma_512) ----
    if (wv == 1) {
        float* CB = (float*)(SM + OFF_CMB);
        *(f32x4*)(CB + lr*CSTR +  0 + 4*g) = d0;
        *(f32x4*)(CB + lr*CSTR + 16 + 4*g) = d1;
        *(f32x4*)(CB + lr*CSTR + 32 + 4*g) = d2;
        *(f32x4*)(CB + lr*CSTR + 48 + 4*g) = d3;
        if (lane < 16) ((float*)(SM + OFF_LACB))[lane] = lacc;
    }
    __syncthreads();
    if (wv == 0) {
        const float* CB = (const float*)(SM + OFF_CMB);
        const f32x4 q0 = *(const f32x4*)(CB + lr*CSTR +  0 + 4*g);
        const f32x4 q1 = *(const f32x4*)(CB + lr*CSTR + 16 + 4*g);
        const f32x4 q2 = *(const f32x4*)(CB + lr*CSTR + 32 + 4*g);
        const f32x4 q3 = *(const f32x4*)(CB + lr*CSTR + 48 + 4*g);
        float dot = d0.x*q0.x + d0.y*q0.y + d0.z*q0.z + d0.w*q0.w
                  + d1.x*q1.x + d1.y*q1.y + d1.z*q1.z + d1.w*q1.w
                  + d2.x*q2.x + d2.y*q2.y + d2.z*q2.z + d2.w*q2.w
                  + d3.x*q3.x + d3.y*q3.y + d3.z*q3.z + d3.w*q3.w;
        dot += __shfl_xor(dot, 16);
        dot += __shfl_xor(dot, 32);
        float lp = lacc + ((const float*)(SM + OFF_LACB))[lr] + __logf(dot);
        if (g == 0) {                      // lanes 0..15: reduce over batch
            lp += __shfl_xor(lp, 1);
            lp += __shfl_xor(lp, 2);
            lp += __shfl_xor(lp, 4);
            lp += __shfl_xor(lp, 8);
            if (lr == 0) atomicAdd(out, lp * (1.0f / BATCH));
        }
    }
}

// ---------------------------------------------------------------------------
extern "C" void kernel_launch(void* const* d_in, const int* in_sizes, int n_in,
                              void* d_out, int out_size, void* d_ws, size_t ws_size,
                              hipStream_t stream) {
    const int*   y  = (const int*)  d_in[0];
    const float* T  = (const float*)d_in[1];
    const float* E  = (const float*)d_in[2];
    const float* Pi = (const float*)d_in[3];
    float* out = (float*)d_out;
    (void)d_ws; (void)ws_size; (void)in_sizes; (void)n_in; (void)out_size;

    hipMemsetAsync(out, 0, sizeof(float), stream);
    hipLaunchKernelGGL(hmm_fb, dim3(BATCH/16), dim3(128), 0, stream,
                       y, T, E, Pi, out);
}